// Round 7
// baseline (66069.977 us; speedup 1.0000x reference)
//
#include <hip/hip_runtime.h>
#include <math.h>

// NDDE forward-Euler DDE solve, D=768, N=8192 steps.
// x_{j+1} = x_j + dt * tanh(Wx x_j + Wy x_{j-10} + b),  dt = tau/10.
// Output: trajectory [D][N+1] fp32, out[i*(N+1)+k] = x_k[i].
//
// NUMERICS ARE FROZEN (passes at absmax 16.0 / thr 16.4): fp64-exact dots
// rounded per-dot to fp32; fp32 adds for z; correctly-rounded fp32 tanh via
// fp64; fp32 state update mul-then-add; identical per-lane column ownership,
// FMA order, and shuffle reduction tree. Round 7 changes ONLY the sync
// protocol (counter-gated detection) — every double entering every FMA is
// bit-identical to rounds 3-6.
//
// Topology (r5, proven): 96 WGs x 256 thr; WG g owns rows [8g,8g+8), 32
// lanes/row, 24 cols/lane; wave 0 polls AND computes rows 0-1. Weights f64
// in 96 pinned VGPRs. LDS: f32 16-slot transposed history.
//
// Sync (new): two-level.
//  - publish: lane c==0 stores (value|tag) 8B pack (relaxed agent) to ring;
//    per wave: s_waitcnt vmcnt(0) then lane0 atomicAdd(cnt[j+1], +2)
//    (its wave's 2 row-stores are drained to the coherence point first).
//  - detect: wave 0 spins on cnt[j]==768 — 64 lanes, SAME address -> one
//    coalesced 4B request per sweep (vs 6 KB/WG data sweeps in r5, which
//    congested MALL). Then one tag-verified 12-pack/lane load (tags absorb
//    any store/add reordering; rare re-sweep), broadcast to LDS, barrier.

#define DD 768
#define NSTEPS 8192
#define NWG 96
#define NT 256
#define ROWS_PER_WG 8
#define COLS_PER_LANE 24
#define RING 16

#define CNT_OFF  0        // (NSTEPS+1) u32, memset to 0 per launch
#define RING_OFF 65536    // RING * DD * 8B packs

__device__ __forceinline__ unsigned long long ld_tag(const unsigned long long* p) {
    return __hip_atomic_load(p, __ATOMIC_RELAXED, __HIP_MEMORY_SCOPE_AGENT);
}

__global__ __launch_bounds__(NT, 1)
void ndde_kernel(const float* __restrict__ x0,
                 const float* __restrict__ tau,
                 const float* __restrict__ Wx,
                 const float* __restrict__ Wy,
                 const float* __restrict__ b,
                 float* __restrict__ out,
                 unsigned long long* __restrict__ ring,
                 unsigned int* __restrict__ cnt)
{
    // Transposed f32 LDS history: column i lives at hist[slot][(i%24)*32+i/24].
    // Read by lane c at [k*32+c] (bank=c, conflict-free; upper half-wave
    // broadcasts); written by wave-0 2-way (free).
    __shared__ float hist[RING][DD];     // 48 KB

    const int tid = threadIdx.x;
    const int g   = blockIdx.x;
    const int r   = tid >> 5;            // local row 0..7
    const int c   = tid & 31;            // lane-within-row 0..31
    const int row = g * ROWS_PER_WG + r;
    const int cb  = c * COLS_PER_LANE;

    const float dtf = tau[0] / 10.0f;

    // ---- stage weights, cvt f32->f64 ONCE (exact; bit-identical FMAs) ----
    double wx[COLS_PER_LANE], wy[COLS_PER_LANE];
    {
        const float* px = Wx + row * DD + cb;
        const float* py = Wy + row * DD + cb;
        #pragma unroll
        for (int i = 0; i < COLS_PER_LANE / 4; ++i) {
            float4 a = *(const float4*)(px + 4 * i);
            wx[4*i+0] = (double)a.x; wx[4*i+1] = (double)a.y;
            wx[4*i+2] = (double)a.z; wx[4*i+3] = (double)a.w;
            float4 d2 = *(const float4*)(py + 4 * i);
            wy[4*i+0] = (double)d2.x; wy[4*i+1] = (double)d2.y;
            wy[4*i+2] = (double)d2.z; wy[4*i+3] = (double)d2.w;
        }
    }

    const float brow = b[row];
    float xrow = x0[row];                // lane c==0 carries x_j[row]
    if (c == 0) out[row * (NSTEPS + 1) + 0] = xrow;

    for (int j = 0; j < NSTEPS; ++j) {
        // re-pin weights every iteration: spilling them is impossible
        #pragma unroll
        for (int i = 0; i < COLS_PER_LANE; ++i) {
            asm volatile("" : "+v"(wx[i]));
            asm volatile("" : "+v"(wy[i]));
        }

        // ---- delayed half: y = x_{j-10} from LDS history; overlaps other
        // WGs' publish window. Values cvt'd f32->f64 at use (exact). ----
        double dy0 = 0.0, dy1 = 0.0;
        if (j <= 10) {
            const float* ys = x0 + cb;
            #pragma unroll
            for (int i = 0; i < COLS_PER_LANE / 4; ++i) {
                float4 v = *(const float4*)(ys + 4 * i);
                dy0 = fma(wy[4*i+0], (double)v.x, dy0);
                dy1 = fma(wy[4*i+1], (double)v.y, dy1);
                dy0 = fma(wy[4*i+2], (double)v.z, dy0);
                dy1 = fma(wy[4*i+3], (double)v.w, dy1);
            }
        } else {
            const float* hs = hist[(j - 10) & (RING - 1)];
            #pragma unroll
            for (int k = 0; k < COLS_PER_LANE; k += 4) {
                float v0 = hs[(k+0)*32 + c];
                float v1 = hs[(k+1)*32 + c];
                float v2 = hs[(k+2)*32 + c];
                float v3 = hs[(k+3)*32 + c];
                dy0 = fma(wy[k+0], (double)v0, dy0);
                dy1 = fma(wy[k+1], (double)v1, dy1);
                dy0 = fma(wy[k+2], (double)v2, dy0);
                dy1 = fma(wy[k+3], (double)v3, dy1);
            }
        }
        double doty = dy0 + dy1;
        #pragma unroll
        for (int off = 1; off < 32; off <<= 1)
            doty += __shfl_xor(doty, off);

        // ---- wave 0: counter-gated detect, then tag-verified fetch ----
        if (j >= 1 && tid < 64) {
            const unsigned tgt = (unsigned)j;
            // cheap spin: 64 lanes, same address -> 1 coalesced request/sweep
            while (__hip_atomic_load(&cnt[j], __ATOMIC_RELAXED,
                                     __HIP_MEMORY_SCOPE_AGENT) < 768u) { }
            // data fetch, tag-verified (tags absorb store/add reordering)
            const unsigned long long* xs =
                ring + (j & (RING - 1)) * DD + tid * 12;
            unsigned long long xv[12];
            for (;;) {
                #pragma unroll
                for (int m = 0; m < 12; ++m) xv[m] = ld_tag(xs + m);
                bool ok = true;
                #pragma unroll
                for (int m = 0; m < 12; ++m)
                    ok &= ((unsigned)(xv[m] >> 32) == tgt);
                if (__all(ok)) break;
            }
            float* hsw = hist[j & (RING - 1)];
            #pragma unroll
            for (int m = 0; m < 12; ++m) {
                int i = tid * 12 + m;
                hsw[(i % 24) * 32 + (i / 24)] =
                    __uint_as_float((unsigned)xv[m]);
            }
        }
        __syncthreads();                 // broadcast visible to all waves

        // ---- live half: Wx · x_j from LDS (x0 global at j==0) ----
        double dx0 = 0.0, dx1 = 0.0;
        if (j == 0) {
            const float* xs = x0 + cb;
            #pragma unroll
            for (int i = 0; i < COLS_PER_LANE / 4; ++i) {
                float4 v = *(const float4*)(xs + 4 * i);
                dx0 = fma(wx[4*i+0], (double)v.x, dx0);
                dx1 = fma(wx[4*i+1], (double)v.y, dx1);
                dx0 = fma(wx[4*i+2], (double)v.z, dx0);
                dx1 = fma(wx[4*i+3], (double)v.w, dx1);
            }
        } else {
            const float* hs = hist[j & (RING - 1)];
            #pragma unroll
            for (int k = 0; k < COLS_PER_LANE; k += 4) {
                float v0 = hs[(k+0)*32 + c];
                float v1 = hs[(k+1)*32 + c];
                float v2 = hs[(k+2)*32 + c];
                float v3 = hs[(k+3)*32 + c];
                dx0 = fma(wx[k+0], (double)v0, dx0);
                dx1 = fma(wx[k+1], (double)v1, dx1);
                dx0 = fma(wx[k+2], (double)v2, dx0);
                dx1 = fma(wx[k+3], (double)v3, dx1);
            }
        }
        double dotx = dx0 + dx1;
        #pragma unroll
        for (int off = 1; off < 32; off <<= 1)
            dotx += __shfl_xor(dotx, off);

        if (c == 0) {
            // z = (dot1_f32 + dot2_f32) + b, all fp32 adds (np's structure)
            float z = __fadd_rn(__fadd_rn((float)dotx, (float)doty), brow);
            float th;
            float az = fabsf(z);
            if (az < 9.3f) th = (float)tanh((double)z);  // correctly-rounded
            else           th = (z > 0.0f) ? 1.0f : -1.0f;
            // x_next = x + dt*F, fp32 mul then fp32 add (no contraction)
            xrow = __fadd_rn(xrow, __fmul_rn(dtf, th));

            // publish: (value|tag) in one relaxed agent-scope 8B store
            unsigned long long pack =
                ((unsigned long long)(unsigned)(j + 1) << 32) |
                (unsigned long long)__float_as_uint(xrow);
            __hip_atomic_store(&ring[((j + 1) & (RING - 1)) * DD + row], pack,
                               __ATOMIC_RELAXED, __HIP_MEMORY_SCOPE_AGENT);
        }
        // drain this wave's 2 row-stores to the coherence point, then one
        // +2 bump of the step counter by lane 0 of the wave
        asm volatile("s_waitcnt vmcnt(0)" ::: "memory");
        if ((tid & 63) == 0) {
            __hip_atomic_fetch_add(&cnt[j + 1], 2u, __ATOMIC_RELAXED,
                                   __HIP_MEMORY_SCOPE_AGENT);
        }
        // trajectory write — off the critical path
        if (c == 0) {
            out[row * (NSTEPS + 1) + (j + 1)] = xrow;
        }
    }
}

extern "C" void kernel_launch(void* const* d_in, const int* in_sizes, int n_in,
                              void* d_out, int out_size, void* d_ws, size_t ws_size,
                              hipStream_t stream) {
    (void)in_sizes; (void)n_in; (void)out_size; (void)ws_size;

    const float* x0  = (const float*)d_in[0];
    const float* tau = (const float*)d_in[1];
    const float* Wx  = (const float*)d_in[2];
    const float* Wy  = (const float*)d_in[3];
    const float* b   = (const float*)d_in[4];
    float* out = (float*)d_out;

    unsigned int* cnt        = (unsigned int*)((char*)d_ws + CNT_OFF);
    unsigned long long* ring = (unsigned long long*)((char*)d_ws + RING_OFF);

    // zero the per-step arrival counters (graph-capture safe); ring needs no
    // init — strict tag==j matching rejects poison and stale replay data.
    hipMemsetAsync(cnt, 0, (NSTEPS + 1) * sizeof(unsigned int), stream);

    ndde_kernel<<<NWG, NT, 0, stream>>>(x0, tau, Wx, Wy, b, out, ring, cnt);
}